// Round 3
// baseline (180.827 us; speedup 1.0000x reference)
//
#include <hip/hip_runtime.h>
#include <stdint.h>

#define L2E 1.44269504088896340736f

typedef _Float16 half8 __attribute__((ext_vector_type(8)));
typedef float floatx4 __attribute__((ext_vector_type(4)));

static __device__ __forceinline__ unsigned short f32_to_f16u(float f) {
  union { _Float16 h; unsigned short s; } cv; cv.h = (_Float16)f; return cv.s;
}

// raw hardware exp2 (no ocml range-check wrapper); inputs here are |x| < 8
static __device__ __forceinline__ float fast_exp2(float x) {
  float r;
  asm("v_exp_f32 %0, %1" : "=v"(r) : "v"(x));
  return r;
}

// ---------------------------------------------------------------------------
// Projection GEMM:  outT[n][o] = sum_c X[c][n]*W[o][c] + b[o]
// X fragments hoisted to registers ONCE per block (32 VGPRs), reused across
// W-quarters. z=0: q,k from depth. z=1,2: v co-halves from rgb (2 quarters
// each) -> rgb read 2x total instead of 4x.
// ---------------------------------------------------------------------------
__global__ __launch_bounds__(256) void proj_kernel(
    const float* __restrict__ rgb,
    const float* __restrict__ depth,
    const float* __restrict__ Wq, const float* __restrict__ bq,
    const float* __restrict__ Wk, const float* __restrict__ bk,
    const float* __restrict__ Wv, const float* __restrict__ bv,
    unsigned short* __restrict__ qT,
    unsigned short* __restrict__ kT,
    unsigned short* __restrict__ v)
{
  __shared__ __align__(16) unsigned short sW[64 * 256];  // 32 KB fp16, swizzled

  const int n0 = blockIdx.x * 64;
  const int b  = blockIdx.y;
  const int z  = blockIdx.z;
  const int t  = threadIdx.x;
  const int w  = t >> 6;
  const int lane = t & 63;
  const int l15 = lane & 15;
  const int q4  = lane >> 4;

  const float* X = (z == 0) ? depth : rgb;
  const float* xb = X + (size_t)b * 256 * 4096;
  const int n_row = n0 + 16 * w + l15;

  // ---- hoist A fragments (X column gather) once: 64 dword loads -> 32 VGPRs
  half8 a8[8];
#pragma unroll
  for (int ks = 0; ks < 8; ks++) {
#pragma unroll
    for (int j = 0; j < 8; j++) {
      int c = ks * 32 + q4 * 8 + j;
      a8[ks][j] = (_Float16)xb[(size_t)c * 4096 + n_row];
    }
  }

  const int nq = (z == 0) ? 1 : 2;
  for (int qd = 0; qd < nq; qd++) {
    const int colbase = (z == 0) ? 0 : (z - 1) * 128 + qd * 64;
    __syncthreads();  // prev quarter's LDS reads done before overwrite

    // ---- stage W quarter: 2048 16B-chunks, linear chunk L (conflict-free
    // writes). og = L>>5, phys = L&31, logical ci = phys ^ (og&7).
#pragma unroll
    for (int it = 0; it < 8; it++) {
      int L = it * 256 + t;
      int og = L >> 5;
      int phys = L & 31;
      int ci = phys ^ (og & 7);
      const float* wr;
      if (z == 0) wr = (og < 32) ? (Wq + (size_t)og * 256) : (Wk + (size_t)(og - 32) * 256);
      else        wr = Wv + (size_t)(colbase + og) * 256;
      float4 w0 = *(const float4*)(wr + ci * 8);
      float4 w1 = *(const float4*)(wr + ci * 8 + 4);
      half8 h;
      h[0] = (_Float16)w0.x; h[1] = (_Float16)w0.y; h[2] = (_Float16)w0.z; h[3] = (_Float16)w0.w;
      h[4] = (_Float16)w1.x; h[5] = (_Float16)w1.y; h[6] = (_Float16)w1.z; h[7] = (_Float16)w1.w;
      *(half8*)&sW[(size_t)L * 8] = h;
    }

    float bias[4];
#pragma unroll
    for (int ct = 0; ct < 4; ct++) {
      int og = ct * 16 + l15;
      if (z == 0) bias[ct] = (og < 32) ? bq[og] : bk[og - 32];
      else        bias[ct] = bv[colbase + og];
    }
    __syncthreads();

    floatx4 acc[4];
#pragma unroll
    for (int i = 0; i < 4; i++) acc[i] = (floatx4){0.f, 0.f, 0.f, 0.f};

#pragma unroll
    for (int ks = 0; ks < 8; ks++) {
      const int ci = ks * 4 + q4;
#pragma unroll
      for (int ct = 0; ct < 4; ct++) {
        int og = ct * 16 + l15;
        half8 bf = *(const half8*)&sW[og * 256 + ((ci ^ (og & 7)) * 8)];
        acc[ct] = __builtin_amdgcn_mfma_f32_16x16x32_f16(a8[ks], bf, acc[ct], 0, 0, 0);
      }
    }

    __syncthreads();  // done reading sW before epilogue reuse / next stage

    if (z == 0) {
#pragma unroll
      for (int ct = 0; ct < 4; ct++) {
        int og = ct * 16 + l15;
#pragma unroll
        for (int r = 0; r < 4; r++) {
          int n = n0 + 16 * w + q4 * 4 + r;
          unsigned short hv = f32_to_f16u(acc[ct][r] + bias[ct]);
          if (og < 32) qT[((size_t)b * 4096 + n) * 32 + og] = hv;
          else         kT[((size_t)b * 4096 + n) * 32 + (og - 32)] = hv;
        }
      }
    } else {
      unsigned short* tile = sW;  // reuse: [64 co][pitch 72]
#pragma unroll
      for (int ct = 0; ct < 4; ct++) {
#pragma unroll
        for (int r = 0; r < 4; r++) {
          int co_l = ct * 16 + l15;
          int nl = 16 * w + q4 * 4 + r;
          tile[co_l * 72 + nl] = f32_to_f16u(acc[ct][r] + bias[ct]);
        }
      }
      __syncthreads();
#pragma unroll
      for (int it = 0; it < 2; it++) {
        int co_l = it * 32 + (t >> 3);
        int ch = t & 7;
        int4 val = *(const int4*)&tile[co_l * 72 + ch * 8];
        *(int4*)&v[((size_t)b * 256 + colbase + co_l) * 4096 + n0 + ch * 8] = val;
      }
    }
  }
}

// ---------------------------------------------------------------------------
// Flash attention, split-m. S phase: waves split by n (wave w computes P for
// its 16 rows). PV phase: waves split by CO (wave w owns co w*64..+63).
// V is NOT staged in LDS at all: with the co-split, each wave's V-fragment
// is a contiguous 16B/lane read from global v[b][co][m] (same pattern as K)
// -> V and K both live in registers, prefetched one iter ahead. LDS carries
// only P (cross-wave share), double-buffered -> ONE barrier per iteration.
// exp via raw v_exp_f32 (no ocml wrapper).
// ---------------------------------------------------------------------------
__global__ __launch_bounds__(256, 3) void attn_kernel(
    const unsigned short* __restrict__ qT,  // [b][n][32] fp16
    const unsigned short* __restrict__ kT,  // [b][m][32] fp16
    const unsigned short* __restrict__ v,   // [b][co][m] fp16
    unsigned short* __restrict__ Op,        // [chunk][b][co][n] fp16 (unnormalized)
    float* __restrict__ lW)                 // [chunk][b][n]
{
  __shared__ __align__(16) unsigned char smem[18432];
  // sP: [2 buf][4 n-regions][16 rows][pitch 40] u16 = 10240 B (epilogue
  // reuses smem as [128 co][pitch 72] u16 = 18432 B)
  unsigned short* sP = (unsigned short*)smem;

  const int n0 = blockIdx.x * 64;
  const int b  = blockIdx.y;
  const int chunk = blockIdx.z;
  const int t  = threadIdx.x;
  const int w  = t >> 6;
  const int lane = t & 63;
  const int l15 = lane & 15;
  const int q4  = lane >> 4;

  half8 aq = *(const half8*)(qT + ((size_t)b * 4096 + n0 + 16 * w + l15) * 32 + q4 * 8);

  // K frag: rows M+l15 / M+16+l15, k = q4*8+j  (16B/lane, coalesced)
  const unsigned short* kL = kT + (size_t)b * 4096 * 32 + (size_t)l15 * 32 + q4 * 8;
  // V frag (B-operand): col = co = w*64 + ct*16 + l15, k = m = m0 + q4*8+j
  // -> contiguous 16B at v[b][co][m0 + q4*8]
  const unsigned short* vL = v + ((size_t)b * 256 + w * 64 + l15) * 4096 + q4 * 8;

  float lsum[4] = {0.f, 0.f, 0.f, 0.f};
  floatx4 acc[16];  // [ct co-tile][nt n-tile] -> acc[ct*4+nt]
#pragma unroll
  for (int ct = 0; ct < 16; ct++) acc[ct] = (floatx4){0.f, 0.f, 0.f, 0.f};
  const floatx4 zf = (floatx4){0.f, 0.f, 0.f, 0.f};

  const int mbase = chunk * 1024;

  // prologue: K(0), V(0) -> regs
  half8 kc0 = *(const half8*)(kL + (size_t)mbase * 32);
  half8 kc1 = *(const half8*)(kL + (size_t)(mbase + 16) * 32);
  half8 vc0 = *(const half8*)(vL + mbase);
  half8 vc1 = *(const half8*)(vL + 65536 + mbase);
  half8 vc2 = *(const half8*)(vL + 131072 + mbase);
  half8 vc3 = *(const half8*)(vL + 196608 + mbase);

  unsigned short* sPw = sP + w * 640;

  for (int it = 0; it < 32; ++it) {
    const int m0 = mbase + it * 32;
    const int bufo = (it & 1) * 2560;
    // prefetch next iter's K (2) + V (4) into separate regs
    half8 kn0 = kc0, kn1 = kc1, vn0 = vc0, vn1 = vc1, vn2 = vc2, vn3 = vc3;
    if (it < 31) {
      kn0 = *(const half8*)(kL + (size_t)(m0 + 32) * 32);
      kn1 = *(const half8*)(kL + (size_t)(m0 + 48) * 32);
      vn0 = *(const half8*)(vL + m0 + 32);
      vn1 = *(const half8*)(vL + 65536 + m0 + 32);
      vn2 = *(const half8*)(vL + 131072 + m0 + 32);
      vn3 = *(const half8*)(vL + 196608 + m0 + 32);
    }

    // S = Q K^T for this wave's 16 n x 32 m
    floatx4 s0 = __builtin_amdgcn_mfma_f32_16x16x32_f16(aq, kc0, zf, 0, 0, 0);
    floatx4 s1 = __builtin_amdgcn_mfma_f32_16x16x32_f16(aq, kc1, zf, 0, 0, 0);

    float p0[4], p1[4];
#pragma unroll
    for (int r = 0; r < 4; r++) {
      p0[r] = fast_exp2(s0[r] * L2E);
      p1[r] = fast_exp2(s1[r] * L2E);
      lsum[r] += p0[r] + p1[r];
    }
#pragma unroll
    for (int r = 0; r < 4; r++) {
      int row = q4 * 4 + r;
      sPw[bufo + row * 40 + l15]      = f32_to_f16u(p0[r]);
      sPw[bufo + row * 40 + 16 + l15] = f32_to_f16u(p1[r]);
    }
    // own P writes (and last iter's ap reads) complete before the barrier;
    // the single barrier is safe because buffers alternate.
    asm volatile("s_waitcnt lgkmcnt(0)" ::: "memory");
    __builtin_amdgcn_s_barrier();
    asm volatile("" ::: "memory");

    // P-frags for ALL 64 n (rows nt*16+l15, k = m = q4*8+j)
    half8 ap[4];
#pragma unroll
    for (int nt = 0; nt < 4; nt++)
      ap[nt] = *(const half8*)&sP[bufo + nt * 640 + l15 * 40 + q4 * 8];

#pragma unroll
    for (int ct = 0; ct < 4; ct++) {
      half8 bv8 = (ct == 0) ? vc0 : (ct == 1) ? vc1 : (ct == 2) ? vc2 : vc3;
#pragma unroll
      for (int nt = 0; nt < 4; nt++)
        acc[ct * 4 + nt] = __builtin_amdgcn_mfma_f32_16x16x32_f16(ap[nt], bv8, acc[ct * 4 + nt], 0, 0, 0);
    }

    kc0 = kn0; kc1 = kn1; vc0 = vn0; vc1 = vn1; vc2 = vn2; vc3 = vn3;
  }

  // lsum reduce (S phase split by n: wave w owns rows n0+16w+..)
#pragma unroll
  for (int off = 1; off < 16; off <<= 1) {
#pragma unroll
    for (int r = 0; r < 4; r++) lsum[r] += __shfl_xor(lsum[r], off);
  }
  if (l15 == 0) {
#pragma unroll
    for (int r = 0; r < 4; r++)
      lW[((size_t)chunk * 4 + b) * 4096 + n0 + 16 * w + q4 * 4 + r] = lsum[r];
  }

  // epilogue: wave w owns co w*64..w*64+63, all 64 n.
  // pass p stages co p*128..p*128+127 (waves with w>>1 == p write).
  unsigned short* sO = (unsigned short*)smem;  // [128 co][pitch 72]
#pragma unroll
  for (int pass = 0; pass < 2; pass++) {
    __syncthreads();
    if ((w >> 1) == pass) {
#pragma unroll
      for (int ct = 0; ct < 4; ct++) {
        int co_l = (w & 1) * 64 + ct * 16 + l15;
#pragma unroll
        for (int nt = 0; nt < 4; nt++) {
#pragma unroll
          for (int r = 0; r < 4; r++) {
            int nl = nt * 16 + q4 * 4 + r;
            sO[co_l * 72 + nl] = f32_to_f16u(acc[ct * 4 + nt][r]);
          }
        }
      }
    }
    __syncthreads();
#pragma unroll
    for (int s = 0; s < 4; s++) {
      int co_l = s * 32 + (t >> 3);
      int ch = t & 7;
      int4 val = *(const int4*)&sO[co_l * 72 + ch * 8];
      *(int4*)&Op[(((size_t)chunk * 4 + b) * 256 + pass * 128 + co_l) * 4096 + n0 + ch * 8] = val;
    }
  }
}

// ---------------------------------------------------------------------------
// Combine: out[b][co][n] = sum_ch Op[ch][b][co][n] / sum_ch lW[ch][b][n]
// ---------------------------------------------------------------------------
__global__ __launch_bounds__(256) void combine_kernel(
    const unsigned short* __restrict__ Op,
    const float* __restrict__ lW,
    float* __restrict__ out)
{
  const int t = threadIdx.x;
  const int b = blockIdx.y;
  const size_t n8 = (size_t)blockIdx.x * 2048 + (size_t)t * 8;
  const int co0 = blockIdx.z * 8;

  float sum[8] = {0.f, 0.f, 0.f, 0.f, 0.f, 0.f, 0.f, 0.f};
#pragma unroll
  for (int ch = 0; ch < 4; ch++) {
    const float* lp = lW + ((size_t)ch * 4 + b) * 4096 + n8;
    float4 a0 = *(const float4*)lp;
    float4 a1 = *(const float4*)(lp + 4);
    sum[0] += a0.x; sum[1] += a0.y; sum[2] += a0.z; sum[3] += a0.w;
    sum[4] += a1.x; sum[5] += a1.y; sum[6] += a1.z; sum[7] += a1.w;
  }
  float rl[8];
#pragma unroll
  for (int i = 0; i < 8; i++) rl[i] = 1.0f / sum[i];

#pragma unroll
  for (int cc = 0; cc < 8; cc++) {
    int co = co0 + cc;
    float o[8] = {0.f, 0.f, 0.f, 0.f, 0.f, 0.f, 0.f, 0.f};
#pragma unroll
    for (int ch = 0; ch < 4; ch++) {
      half8 hv = *(const half8*)&Op[(((size_t)ch * 4 + b) * 256 + co) * 4096 + n8];
#pragma unroll
      for (int i = 0; i < 8; i++) o[i] += (float)hv[i];
    }
    float* op = out + ((size_t)b * 256 + co) * 4096 + n8;
    float4 r0, r1;
    r0.x = o[0] * rl[0]; r0.y = o[1] * rl[1]; r0.z = o[2] * rl[2]; r0.w = o[3] * rl[3];
    r1.x = o[4] * rl[4]; r1.y = o[5] * rl[5]; r1.z = o[6] * rl[6]; r1.w = o[7] * rl[7];
    *(float4*)op = r0;
    *(float4*)(op + 4) = r1;
  }
}

extern "C" void kernel_launch(void* const* d_in, const int* in_sizes, int n_in,
                              void* d_out, int out_size, void* d_ws, size_t ws_size,
                              hipStream_t stream) {
  const float* rgb   = (const float*)d_in[0];
  const float* depth = (const float*)d_in[1];
  const float* Wq    = (const float*)d_in[2];
  const float* bq    = (const float*)d_in[3];
  const float* Wk    = (const float*)d_in[4];
  const float* bk    = (const float*)d_in[5];
  const float* Wv    = (const float*)d_in[6];
  const float* bv    = (const float*)d_in[7];
  float* out = (float*)d_out;

  unsigned short* qT = (unsigned short*)d_ws;             // 1 MB
  unsigned short* kT = qT + (size_t)4 * 4096 * 32;        // 1 MB
  unsigned short* vW = kT + (size_t)4 * 4096 * 32;        // 8 MB
  unsigned short* Op = vW + (size_t)4 * 256 * 4096;       // 33.5 MB (4 chunks)
  float* lW = (float*)(Op + (size_t)4 * 4 * 256 * 4096);  // 256 KB

  dim3 pg(64, 4, 3);
  proj_kernel<<<pg, 256, 0, stream>>>(rgb, depth, Wq, bq, Wk, bk, Wv, bv, qT, kT, vW);
  dim3 ag(64, 4, 4);
  attn_kernel<<<ag, 256, 0, stream>>>(qT, kT, vW, Op, lW);
  dim3 cg(2, 4, 32);
  combine_kernel<<<cg, 256, 0, stream>>>(Op, lW, out);
}

// Round 4
// 171.493 us; speedup vs baseline: 1.0544x; 1.0544x over previous
//
#include <hip/hip_runtime.h>
#include <stdint.h>

#define L2E 1.44269504088896340736f

typedef _Float16 half8 __attribute__((ext_vector_type(8)));
typedef float floatx4 __attribute__((ext_vector_type(4)));

static __device__ __forceinline__ unsigned short f32_to_f16u(float f) {
  union { _Float16 h; unsigned short s; } cv; cv.h = (_Float16)f; return cv.s;
}

// raw hardware exp2 (no ocml wrapper); inputs here are small (|x| < 16)
static __device__ __forceinline__ float fast_exp2(float x) {
  float r;
  asm("v_exp_f32 %0, %1" : "=v"(r) : "v"(x));
  return r;
}

typedef __attribute__((address_space(3))) unsigned int as3_uint;
typedef __attribute__((address_space(1))) const unsigned int as1_cuint;

// async global->LDS, 16B per lane; HW dest = wave-uniform base + lane*16
static __device__ __forceinline__ void async16(const void* g, void* l) {
  __builtin_amdgcn_global_load_lds((as1_cuint*)g, (as3_uint*)l, 16, 0, 0);
}

// ---------------------------------------------------------------------------
// Projection GEMM:  outT[n][o] = sum_c X[c][n]*W[o][c] + b[o]
// X tile [256 c][64 n] staged to LDS fp16 (pitch 76) via COALESCED float4
// reads (replaces the old 64-scalar global column gather). A-frags hoisted
// once per block. W staged in 32-row subtiles (16 KB) -> LDS total 55.3 KB.
// z=0: s=0 -> q (Wq), s=1 -> k (Wk), from depth.
// z=1,2: 4 subtiles of 32 co each, v from rgb.
// ---------------------------------------------------------------------------
__global__ __launch_bounds__(256) void proj_kernel(
    const float* __restrict__ rgb,
    const float* __restrict__ depth,
    const float* __restrict__ Wq, const float* __restrict__ bq,
    const float* __restrict__ Wk, const float* __restrict__ bk,
    const float* __restrict__ Wv, const float* __restrict__ bv,
    unsigned short* __restrict__ qT,
    unsigned short* __restrict__ kT,
    unsigned short* __restrict__ v)
{
  __shared__ __align__(16) unsigned short sX[256 * 76];  // 38912 B
  __shared__ __align__(16) unsigned short sW[32 * 256];  // 16384 B

  const int n0 = blockIdx.x * 64;
  const int b  = blockIdx.y;
  const int z  = blockIdx.z;
  const int t  = threadIdx.x;
  const int w  = t >> 6;
  const int lane = t & 63;
  const int l15 = lane & 15;
  const int q4  = lane >> 4;

  const float* X = (z == 0) ? depth : rgb;
  const float* xb = X + (size_t)b * 256 * 4096 + n0;

  // ---- stage X tile: 2048 half8-chunks; chunk h: c = h>>3, n-octet = h&7
#pragma unroll
  for (int i = 0; i < 8; i++) {
    int h = i * 256 + t;
    int c = h >> 3, oct = h & 7;
    const float* src = xb + (size_t)c * 4096 + oct * 8;
    float4 x0 = *(const float4*)src;
    float4 x1 = *(const float4*)(src + 4);
    half8 hh;
    hh[0] = (_Float16)x0.x; hh[1] = (_Float16)x0.y; hh[2] = (_Float16)x0.z; hh[3] = (_Float16)x0.w;
    hh[4] = (_Float16)x1.x; hh[5] = (_Float16)x1.y; hh[6] = (_Float16)x1.z; hh[7] = (_Float16)x1.w;
    *(half8*)&sX[c * 76 + oct * 8] = hh;
  }
  __syncthreads();

  // ---- hoist A-frags once (reused across all subtiles): 64 ds_read_u16
  half8 a8[8];
#pragma unroll
  for (int ks = 0; ks < 8; ks++) {
#pragma unroll
    for (int j = 0; j < 8; j++) {
      a8[ks][j] = *(const _Float16*)&sX[(ks * 32 + q4 * 8 + j) * 76 + 16 * w + l15];
    }
  }

  const int ns = (z == 0) ? 2 : 4;
  for (int s = 0; s < ns; s++) {
    const int colbase = (z == 0) ? 0 : (z - 1) * 128 + s * 32;
    __syncthreads();  // prev subtile's sW reads done before overwrite

    // ---- stage W subtile (32 o x 256 c): 1024 16B-chunks, swizzled
#pragma unroll
    for (int i = 0; i < 4; i++) {
      int L = i * 256 + t;
      int og = L >> 5;
      int phys = L & 31;
      int ci = phys ^ (og & 7);
      const float* wr;
      if (z == 0) wr = ((s == 0) ? Wq : Wk) + (size_t)og * 256;
      else        wr = Wv + (size_t)(colbase + og) * 256;
      float4 w0 = *(const float4*)(wr + ci * 8);
      float4 w1 = *(const float4*)(wr + ci * 8 + 4);
      half8 h;
      h[0] = (_Float16)w0.x; h[1] = (_Float16)w0.y; h[2] = (_Float16)w0.z; h[3] = (_Float16)w0.w;
      h[4] = (_Float16)w1.x; h[5] = (_Float16)w1.y; h[6] = (_Float16)w1.z; h[7] = (_Float16)w1.w;
      *(half8*)&sW[(size_t)L * 8] = h;
    }

    float bias2[2];
#pragma unroll
    for (int ct = 0; ct < 2; ct++) {
      int og = ct * 16 + l15;
      if (z == 0) bias2[ct] = (s == 0) ? bq[og] : bk[og];
      else        bias2[ct] = bv[colbase + og];
    }
    __syncthreads();

    floatx4 acc2[2];
    acc2[0] = (floatx4){0.f, 0.f, 0.f, 0.f};
    acc2[1] = (floatx4){0.f, 0.f, 0.f, 0.f};

#pragma unroll
    for (int ks = 0; ks < 8; ks++) {
      const int ci = ks * 4 + q4;
#pragma unroll
      for (int ct = 0; ct < 2; ct++) {
        int og = ct * 16 + l15;
        half8 bf = *(const half8*)&sW[og * 256 + ((ci ^ (og & 7)) * 8)];
        acc2[ct] = __builtin_amdgcn_mfma_f32_16x16x32_f16(a8[ks], bf, acc2[ct], 0, 0, 0);
      }
    }

    __syncthreads();  // done reading sW before epilogue reuse / next stage

    if (z == 0) {
#pragma unroll
      for (int ct = 0; ct < 2; ct++) {
        int og = ct * 16 + l15;
#pragma unroll
        for (int r = 0; r < 4; r++) {
          int n = n0 + 16 * w + q4 * 4 + r;
          unsigned short hv = f32_to_f16u(acc2[ct][r] + bias2[ct]);
          if (s == 0) qT[((size_t)b * 4096 + n) * 32 + og] = hv;
          else        kT[((size_t)b * 4096 + n) * 32 + og] = hv;
        }
      }
    } else {
      unsigned short* tile = sW;  // reuse: [32 co][pitch 72]
#pragma unroll
      for (int ct = 0; ct < 2; ct++) {
#pragma unroll
        for (int r = 0; r < 4; r++) {
          int co_l = ct * 16 + l15;
          int nl = 16 * w + q4 * 4 + r;
          tile[co_l * 72 + nl] = f32_to_f16u(acc2[ct][r] + bias2[ct]);
        }
      }
      __syncthreads();
      {
        int co_l = t >> 3;
        int ch = t & 7;
        int4 val = *(const int4*)&tile[co_l * 72 + ch * 8];
        *(int4*)&v[((size_t)b * 256 + colbase + co_l) * 4096 + n0 + ch * 8] = val;
      }
    }
  }
}

// ---------------------------------------------------------------------------
// Wave-private V staging: wave w stages its own 64 co rows [w*64, w*64+64)
// of the [256 co][32 m] tile. Phys chunk p of row c holds logical
// p ^ ((c>>1)&3) (pre-swizzled global source, linear LDS dest).
// dst = smem + slot*16384 + w*4096; HW adds lane*16.
// ---------------------------------------------------------------------------
static __device__ __forceinline__ void stage_vp(
    const unsigned short* __restrict__ vB, unsigned char* dst,
    int m0, int lane, int w)
{
#pragma unroll
  for (int j = 0; j < 4; j++) {
    int c = w * 64 + j * 16 + (lane >> 2);
    int p = lane & 3;
    int lc = p ^ ((c >> 1) & 3);
    async16(&vB[(size_t)c * 4096 + m0 + lc * 8], dst + j * 1024);
  }
}

// ---------------------------------------------------------------------------
// Flash attention, split-m. S phase split by n, PV phase split by co.
// V: wave-private LDS double-buffer via global_load_lds (no cross-wave dep
// -> no barrier protection needed; only the wave's own counted vmcnt).
// P: cross-wave LDS double-buffer -> ONE barrier per iteration.
// K: registers, prefetched 1 iter ahead, alternating regsets (no copies).
// Per iter: issue 6 prefetch loads, vmcnt(6), QK, exp(v_exp), store P,
// lgkm, barrier, read P(all n)+V(own co), 16 PV MFMA.
// ---------------------------------------------------------------------------
__global__ __launch_bounds__(256, 4) void attn_kernel(
    const unsigned short* __restrict__ qT,  // [b][n][32] fp16
    const unsigned short* __restrict__ kT,  // [b][m][32] fp16
    const unsigned short* __restrict__ v,   // [b][co][m] fp16
    unsigned short* __restrict__ Op,        // [chunk][b][co][n] fp16 (unnormalized)
    float* __restrict__ lW)                 // [chunk][b][n]
{
  __shared__ __align__(16) unsigned char smem[43008];
  // V slot0: [0,16384), slot1: [16384,32768): [4 waves][64 co][32 m] swizzled
  // sP: [32768, 43008): 2 slots x [4 regions][16 rows][pitch 40] u16
  unsigned short* sP = (unsigned short*)(smem + 32768);

  const int n0 = blockIdx.x * 64;
  const int b  = blockIdx.y;
  const int chunk = blockIdx.z;
  const int t  = threadIdx.x;
  const int w  = t >> 6;
  const int lane = t & 63;
  const int l15 = lane & 15;
  const int q4  = lane >> 4;

  half8 aq = *(const half8*)(qT + ((size_t)b * 4096 + n0 + 16 * w + l15) * 32 + q4 * 8);

  const unsigned short* vB = v + (size_t)b * 256 * 4096;
  const unsigned short* kL = kT + (size_t)b * 4096 * 32 + (size_t)l15 * 32 + q4 * 8;

  float lsum[4] = {0.f, 0.f, 0.f, 0.f};
  floatx4 acc[16];  // [ct co-tile][nt n-tile]
#pragma unroll
  for (int ct = 0; ct < 16; ct++) acc[ct] = (floatx4){0.f, 0.f, 0.f, 0.f};
  const floatx4 zf = (floatx4){0.f, 0.f, 0.f, 0.f};

  const int mbase = chunk * 1024;

  // prologue: V(0) -> slot0 (own region), K(0) -> regset A
  stage_vp(vB, smem + (w << 12), mbase, lane, w);
  half8 kA0 = *(const half8*)(kL + (size_t)mbase * 32);
  half8 kA1 = *(const half8*)(kL + (size_t)(mbase + 16) * 32);
  half8 kB0{}, kB1{};

#define ATTN_BODY(IT_, KC0, KC1, KN0, KN1, PF)                                   \
  {                                                                              \
    const int it_ = (IT_);                                                       \
    const int m0_ = mbase + it_ * 32;                                            \
    asm volatile("" ::: "memory");                                               \
    if (PF) {                                                                    \
      stage_vp(vB, smem + ((((it_ + 1) & 1) << 14) + (w << 12)), m0_ + 32, lane, w); \
      KN0 = *(const half8*)(kL + (size_t)(m0_ + 32) * 32);                       \
      KN1 = *(const half8*)(kL + (size_t)(m0_ + 48) * 32);                       \
      asm volatile("s_waitcnt vmcnt(6)" ::: "memory");                           \
    } else {                                                                     \
      asm volatile("s_waitcnt vmcnt(0)" ::: "memory");                           \
    }                                                                            \
    floatx4 s0 = __builtin_amdgcn_mfma_f32_16x16x32_f16(aq, KC0, zf, 0, 0, 0);   \
    floatx4 s1 = __builtin_amdgcn_mfma_f32_16x16x32_f16(aq, KC1, zf, 0, 0, 0);   \
    float p0[4], p1[4];                                                          \
    _Pragma("unroll") for (int r = 0; r < 4; r++) {                              \
      p0[r] = fast_exp2(s0[r] * L2E);                                            \
      p1[r] = fast_exp2(s1[r] * L2E);                                            \
      lsum[r] += p0[r] + p1[r];                                                  \
    }                                                                            \
    unsigned short* sPw_ = sP + ((it_ & 1) ? 2560 : 0) + w * 640;                \
    _Pragma("unroll") for (int r = 0; r < 4; r++) {                              \
      int row = q4 * 4 + r;                                                      \
      sPw_[row * 40 + l15]      = f32_to_f16u(p0[r]);                            \
      sPw_[row * 40 + 16 + l15] = f32_to_f16u(p1[r]);                            \
    }                                                                            \
    asm volatile("s_waitcnt lgkmcnt(0)" ::: "memory");                           \
    __builtin_amdgcn_s_barrier();                                                \
    asm volatile("s_waitcnt lgkmcnt(0)" ::: "memory");                           \
    const unsigned short* sPb_ = sP + ((it_ & 1) ? 2560 : 0);                    \
    half8 ap[4];                                                                 \
    _Pragma("unroll") for (int nt = 0; nt < 4; nt++)                             \
      ap[nt] = *(const half8*)&sPb_[nt * 640 + l15 * 40 + q4 * 8];               \
    const unsigned short* sVb_ = (const unsigned short*)(smem + ((it_ & 1) << 14)); \
    _Pragma("unroll") for (int ct = 0; ct < 4; ct++) {                           \
      int co = w * 64 + ct * 16 + l15;                                           \
      half8 bv8 = *(const half8*)&sVb_[co * 32 + ((q4 ^ ((co >> 1) & 3)) * 8)];  \
      _Pragma("unroll") for (int nt = 0; nt < 4; nt++)                           \
        acc[ct * 4 + nt] = __builtin_amdgcn_mfma_f32_16x16x32_f16(ap[nt], bv8, acc[ct * 4 + nt], 0, 0, 0); \
    }                                                                            \
  }

  for (int it2 = 0; it2 < 16; ++it2) {
    ATTN_BODY(2 * it2,     kA0, kA1, kB0, kB1, true)
    ATTN_BODY(2 * it2 + 1, kB0, kB1, kA0, kA1, (it2 < 15))
  }
#undef ATTN_BODY

  // lsum reduce (S phase split by n: wave w owns rows n0+16w+..)
#pragma unroll
  for (int off = 1; off < 16; off <<= 1) {
#pragma unroll
    for (int r = 0; r < 4; r++) lsum[r] += __shfl_xor(lsum[r], off);
  }
  if (l15 == 0) {
#pragma unroll
    for (int r = 0; r < 4; r++)
      lW[((size_t)chunk * 4 + b) * 4096 + n0 + 16 * w + q4 * 4 + r] = lsum[r];
  }

  // epilogue: wave w owns co w*64..w*64+63, all 64 n.
  unsigned short* sO = (unsigned short*)smem;  // [128 co][pitch 72]
#pragma unroll
  for (int pass = 0; pass < 2; pass++) {
    __syncthreads();
    if ((w >> 1) == pass) {
#pragma unroll
      for (int ct = 0; ct < 4; ct++) {
        int co_l = (w & 1) * 64 + ct * 16 + l15;
#pragma unroll
        for (int nt = 0; nt < 4; nt++) {
#pragma unroll
          for (int r = 0; r < 4; r++) {
            int nl = nt * 16 + q4 * 4 + r;
            sO[co_l * 72 + nl] = f32_to_f16u(acc[ct * 4 + nt][r]);
          }
        }
      }
    }
    __syncthreads();
#pragma unroll
    for (int s = 0; s < 4; s++) {
      int co_l = s * 32 + (t >> 3);
      int ch = t & 7;
      int4 val = *(const int4*)&sO[co_l * 72 + ch * 8];
      *(int4*)&Op[(((size_t)chunk * 4 + b) * 256 + pass * 128 + co_l) * 4096 + n0 + ch * 8] = val;
    }
  }
}

// ---------------------------------------------------------------------------
// Combine: out[b][co][n] = sum_ch Op[ch][b][co][n] / sum_ch lW[ch][b][n]
// ---------------------------------------------------------------------------
__global__ __launch_bounds__(256) void combine_kernel(
    const unsigned short* __restrict__ Op,
    const float* __restrict__ lW,
    float* __restrict__ out)
{
  const int t = threadIdx.x;
  const int b = blockIdx.y;
  const size_t n8 = (size_t)blockIdx.x * 2048 + (size_t)t * 8;
  const int co0 = blockIdx.z * 4;

  float sum[8] = {0.f, 0.f, 0.f, 0.f, 0.f, 0.f, 0.f, 0.f};
#pragma unroll
  for (int ch = 0; ch < 4; ch++) {
    const float* lp = lW + ((size_t)ch * 4 + b) * 4096 + n8;
    float4 a0 = *(const float4*)lp;
    float4 a1 = *(const float4*)(lp + 4);
    sum[0] += a0.x; sum[1] += a0.y; sum[2] += a0.z; sum[3] += a0.w;
    sum[4] += a1.x; sum[5] += a1.y; sum[6] += a1.z; sum[7] += a1.w;
  }
  float rl[8];
#pragma unroll
  for (int i = 0; i < 8; i++) rl[i] = 1.0f / sum[i];

#pragma unroll
  for (int cc = 0; cc < 4; cc++) {
    int co = co0 + cc;
    float o[8] = {0.f, 0.f, 0.f, 0.f, 0.f, 0.f, 0.f, 0.f};
#pragma unroll
    for (int ch = 0; ch < 4; ch++) {
      half8 hv = *(const half8*)&Op[(((size_t)ch * 4 + b) * 256 + co) * 4096 + n8];
#pragma unroll
      for (int i = 0; i < 8; i++) o[i] += (float)hv[i];
    }
    float* op = out + ((size_t)b * 256 + co) * 4096 + n8;
    float4 r0, r1;
    r0.x = o[0] * rl[0]; r0.y = o[1] * rl[1]; r0.z = o[2] * rl[2]; r0.w = o[3] * rl[3];
    r1.x = o[4] * rl[4]; r1.y = o[5] * rl[5]; r1.z = o[6] * rl[6]; r1.w = o[7] * rl[7];
    *(float4*)op = r0;
    *(float4*)(op + 4) = r1;
  }
}

extern "C" void kernel_launch(void* const* d_in, const int* in_sizes, int n_in,
                              void* d_out, int out_size, void* d_ws, size_t ws_size,
                              hipStream_t stream) {
  const float* rgb   = (const float*)d_in[0];
  const float* depth = (const float*)d_in[1];
  const float* Wq    = (const float*)d_in[2];
  const float* bq    = (const float*)d_in[3];
  const float* Wk    = (const float*)d_in[4];
  const float* bk    = (const float*)d_in[5];
  const float* Wv    = (const float*)d_in[6];
  const float* bv    = (const float*)d_in[7];
  float* out = (float*)d_out;

  unsigned short* qT = (unsigned short*)d_ws;             // 1 MB
  unsigned short* kT = qT + (size_t)4 * 4096 * 32;        // 1 MB
  unsigned short* vW = kT + (size_t)4 * 4096 * 32;        // 8 MB
  unsigned short* Op = vW + (size_t)4 * 256 * 4096;       // 33.5 MB (4 chunks)
  float* lW = (float*)(Op + (size_t)4 * 4 * 256 * 4096);  // 256 KB

  dim3 pg(64, 4, 3);
  proj_kernel<<<pg, 256, 0, stream>>>(rgb, depth, Wq, bq, Wk, bk, Wv, bv, qT, kT, vW);
  dim3 ag(64, 4, 4);
  attn_kernel<<<ag, 256, 0, stream>>>(qT, kT, vW, Op, lW);
  dim3 cg(2, 4, 64);
  combine_kernel<<<cg, 256, 0, stream>>>(Op, lW, out);
}

// Round 5
// 160.641 us; speedup vs baseline: 1.1257x; 1.0676x over previous
//
#include <hip/hip_runtime.h>
#include <stdint.h>

#define L2E 1.44269504088896340736f

typedef _Float16 half8 __attribute__((ext_vector_type(8)));
typedef float floatx4 __attribute__((ext_vector_type(4)));

static __device__ __forceinline__ unsigned short f32_to_f16u(float f) {
  union { _Float16 h; unsigned short s; } cv; cv.h = (_Float16)f; return cv.s;
}

// raw hardware exp2 (no ocml wrapper); inputs here are small (|x| < 16)
static __device__ __forceinline__ float fast_exp2(float x) {
  float r;
  asm("v_exp_f32 %0, %1" : "=v"(r) : "v"(x));
  return r;
}

typedef __attribute__((address_space(3))) unsigned int as3_uint;
typedef __attribute__((address_space(1))) const unsigned int as1_cuint;

// async global->LDS, 16B per lane; HW dest = wave-uniform base + lane*16
static __device__ __forceinline__ void async16(const void* g, void* l) {
  __builtin_amdgcn_global_load_lds((as1_cuint*)g, (as3_uint*)l, 16, 0, 0);
}

// ---------------------------------------------------------------------------
// Projection GEMM:  outT[n][o] = sum_c X[c][n]*W[o][c] + b[o]
// X tile [256 c][64 n] staged to LDS fp16 (pitch 76) via COALESCED float4
// reads. A-frags hoisted once per block. W staged in 32-row subtiles.
// z=0: s=0 -> q (Wq), s=1 -> k (Wk), from depth.
// z=1,2: 4 subtiles of 32 co each, v from rgb.
// ---------------------------------------------------------------------------
__global__ __launch_bounds__(256) void proj_kernel(
    const float* __restrict__ rgb,
    const float* __restrict__ depth,
    const float* __restrict__ Wq, const float* __restrict__ bq,
    const float* __restrict__ Wk, const float* __restrict__ bk,
    const float* __restrict__ Wv, const float* __restrict__ bv,
    unsigned short* __restrict__ qT,
    unsigned short* __restrict__ kT,
    unsigned short* __restrict__ v)
{
  __shared__ __align__(16) unsigned short sX[256 * 76];  // 38912 B
  __shared__ __align__(16) unsigned short sW[32 * 256];  // 16384 B

  const int n0 = blockIdx.x * 64;
  const int b  = blockIdx.y;
  const int z  = blockIdx.z;
  const int t  = threadIdx.x;
  const int w  = t >> 6;
  const int lane = t & 63;
  const int l15 = lane & 15;
  const int q4  = lane >> 4;

  const float* X = (z == 0) ? depth : rgb;
  const float* xb = X + (size_t)b * 256 * 4096 + n0;

  // ---- stage X tile: 2048 half8-chunks; chunk h: c = h>>3, n-octet = h&7
#pragma unroll
  for (int i = 0; i < 8; i++) {
    int h = i * 256 + t;
    int c = h >> 3, oct = h & 7;
    const float* src = xb + (size_t)c * 4096 + oct * 8;
    float4 x0 = *(const float4*)src;
    float4 x1 = *(const float4*)(src + 4);
    half8 hh;
    hh[0] = (_Float16)x0.x; hh[1] = (_Float16)x0.y; hh[2] = (_Float16)x0.z; hh[3] = (_Float16)x0.w;
    hh[4] = (_Float16)x1.x; hh[5] = (_Float16)x1.y; hh[6] = (_Float16)x1.z; hh[7] = (_Float16)x1.w;
    *(half8*)&sX[c * 76 + oct * 8] = hh;
  }
  __syncthreads();

  // ---- hoist A-frags once (reused across all subtiles)
  half8 a8[8];
#pragma unroll
  for (int ks = 0; ks < 8; ks++) {
#pragma unroll
    for (int j = 0; j < 8; j++) {
      a8[ks][j] = *(const _Float16*)&sX[(ks * 32 + q4 * 8 + j) * 76 + 16 * w + l15];
    }
  }

  const int ns = (z == 0) ? 2 : 4;
  for (int s = 0; s < ns; s++) {
    const int colbase = (z == 0) ? 0 : (z - 1) * 128 + s * 32;
    __syncthreads();  // prev subtile's sW reads done before overwrite

    // ---- stage W subtile (32 o x 256 c): 1024 16B-chunks, swizzled
#pragma unroll
    for (int i = 0; i < 4; i++) {
      int L = i * 256 + t;
      int og = L >> 5;
      int phys = L & 31;
      int ci = phys ^ (og & 7);
      const float* wr;
      if (z == 0) wr = ((s == 0) ? Wq : Wk) + (size_t)og * 256;
      else        wr = Wv + (size_t)(colbase + og) * 256;
      float4 w0 = *(const float4*)(wr + ci * 8);
      float4 w1 = *(const float4*)(wr + ci * 8 + 4);
      half8 h;
      h[0] = (_Float16)w0.x; h[1] = (_Float16)w0.y; h[2] = (_Float16)w0.z; h[3] = (_Float16)w0.w;
      h[4] = (_Float16)w1.x; h[5] = (_Float16)w1.y; h[6] = (_Float16)w1.z; h[7] = (_Float16)w1.w;
      *(half8*)&sW[(size_t)L * 8] = h;
    }

    float bias2[2];
#pragma unroll
    for (int ct = 0; ct < 2; ct++) {
      int og = ct * 16 + l15;
      if (z == 0) bias2[ct] = (s == 0) ? bq[og] : bk[og];
      else        bias2[ct] = bv[colbase + og];
    }
    __syncthreads();

    floatx4 acc2[2];
    acc2[0] = (floatx4){0.f, 0.f, 0.f, 0.f};
    acc2[1] = (floatx4){0.f, 0.f, 0.f, 0.f};

#pragma unroll
    for (int ks = 0; ks < 8; ks++) {
      const int ci = ks * 4 + q4;
#pragma unroll
      for (int ct = 0; ct < 2; ct++) {
        int og = ct * 16 + l15;
        half8 bf = *(const half8*)&sW[og * 256 + ((ci ^ (og & 7)) * 8)];
        acc2[ct] = __builtin_amdgcn_mfma_f32_16x16x32_f16(a8[ks], bf, acc2[ct], 0, 0, 0);
      }
    }

    __syncthreads();  // done reading sW before epilogue reuse / next stage

    if (z == 0) {
#pragma unroll
      for (int ct = 0; ct < 2; ct++) {
        int og = ct * 16 + l15;
#pragma unroll
        for (int r = 0; r < 4; r++) {
          int n = n0 + 16 * w + q4 * 4 + r;
          unsigned short hv = f32_to_f16u(acc2[ct][r] + bias2[ct]);
          if (s == 0) qT[((size_t)b * 4096 + n) * 32 + og] = hv;
          else        kT[((size_t)b * 4096 + n) * 32 + og] = hv;
        }
      }
    } else {
      unsigned short* tile = sW;  // reuse: [32 co][pitch 72]
#pragma unroll
      for (int ct = 0; ct < 2; ct++) {
#pragma unroll
        for (int r = 0; r < 4; r++) {
          int co_l = ct * 16 + l15;
          int nl = 16 * w + q4 * 4 + r;
          tile[co_l * 72 + nl] = f32_to_f16u(acc2[ct][r] + bias2[ct]);
        }
      }
      __syncthreads();
      {
        int co_l = t >> 3;
        int ch = t & 7;
        int4 val = *(const int4*)&tile[co_l * 72 + ch * 8];
        *(int4*)&v[((size_t)b * 256 + colbase + co_l) * 4096 + n0 + ch * 8] = val;
      }
    }
  }
}

// ---------------------------------------------------------------------------
// V staging: [256 co][32 m] fp16, phys chunk p of row c holds logical
// p ^ ((c>>1)&3); pre-swizzled global source + LINEAR LDS dest (the
// global_load_lds contract: wave-uniform base + lane*16).
// ---------------------------------------------------------------------------
static __device__ __forceinline__ void stage_v(
    const unsigned short* __restrict__ vB, unsigned char* sbase,
    int m0, int t, int w)
{
#pragma unroll
  for (int j = 0; j < 4; j++) {
    int lin = j * 256 + t;
    int c = lin >> 2;
    int p = lin & 3;
    int lc = p ^ ((c >> 1) & 3);
    async16(&vB[(size_t)c * 4096 + m0 + lc * 8], sbase + j * 4096 + w * 1024);
  }
}

// ---------------------------------------------------------------------------
// Flash attention, split-m (R2 structure, proven 64.5us, + fast_exp2 +
// XCD-aware block swizzle). S phase: waves split by n. PV phase: waves split
// by co. V double-buffered via global_load_lds, K prefetched to regs,
// counted vmcnt(6) so next-iter loads stay in flight across the barrier.
// Grid: 1D 1024 blocks; o = (p&7) | (x<<3) | ((p>>3)<<9), p = (chunk<<2)|b.
// All 64 blocks of one (b,chunk) -> same XCD: their shared 0.5 MB V slice +
// K/Q slices become L2-resident (cuts the 3.7x HBM over-fetch).
// ---------------------------------------------------------------------------
__global__ __launch_bounds__(256, 4) void attn_kernel(
    const unsigned short* __restrict__ qT,  // [b][n][32] fp16
    const unsigned short* __restrict__ kT,  // [b][m][32] fp16
    const unsigned short* __restrict__ v,   // [b][co][m] fp16
    unsigned short* __restrict__ Op,        // [chunk][b][co][n] fp16 (unnormalized)
    float* __restrict__ lW)                 // [chunk][b][n]
{
  __shared__ __align__(16) unsigned char smem[37888];
  // sV buf0: [0,16384), buf1: [16384,32768)  -- [256 co][32 m] fp16 swizzled
  // sP: [32768, 37888) -- [64 n][pitch 40] u16 (wave w owns rows 16w..16w+15)
  unsigned short* sP = (unsigned short*)(smem + 32768);

  const int o = blockIdx.x;
  const int n0 = ((o >> 3) & 63) * 64;
  const int p  = (o & 7) | ((o >> 9) << 3);
  const int b  = p & 3;
  const int chunk = p >> 2;
  const int t  = threadIdx.x;
  const int w  = t >> 6;
  const int lane = t & 63;
  const int l15 = lane & 15;
  const int q4  = lane >> 4;

  half8 aq = *(const half8*)(qT + ((size_t)b * 4096 + n0 + 16 * w + l15) * 32 + q4 * 8);

  const unsigned short* vB = v + (size_t)b * 256 * 4096;
  const unsigned short* kL = kT + (size_t)b * 4096 * 32 + (size_t)l15 * 32 + q4 * 8;
  unsigned short* sPw = sP + w * 640;

  float lsum[4] = {0.f, 0.f, 0.f, 0.f};
  floatx4 acc[16];  // [ct co-tile][nt n-tile] -> acc[ct*4+nt]
#pragma unroll
  for (int ct = 0; ct < 16; ct++) acc[ct] = (floatx4){0.f, 0.f, 0.f, 0.f};
  const floatx4 zf = (floatx4){0.f, 0.f, 0.f, 0.f};

  const int mbase = chunk * 1024;

  // prologue: V(0) -> buf0, K(0) -> regs
  stage_v(vB, smem, mbase, t, w);
  half8 kc0 = *(const half8*)(kL + (size_t)mbase * 32);
  half8 kc1 = *(const half8*)(kL + (size_t)(mbase + 16) * 32);

  int bufoff = 0;
  for (int it = 0; it < 32; ++it) {
    const int m0 = mbase + it * 32;
    half8 kn0 = kc0, kn1 = kc1;
    if (it < 31) {
      // issue next-iter V stage (4) + K prefetch (2), then wait for THIS
      // iter's 6: allow the 6 just-issued to stay in flight.
      stage_v(vB, smem + (bufoff ^ 16384), m0 + 32, t, w);
      kn0 = *(const half8*)(kL + (size_t)(m0 + 32) * 32);
      kn1 = *(const half8*)(kL + (size_t)(m0 + 48) * 32);
      asm volatile("s_waitcnt vmcnt(6)" ::: "memory");
    } else {
      asm volatile("s_waitcnt vmcnt(0)" ::: "memory");
    }

    // S = Q K^T for this wave's 16 n x 32 m (K in regs)
    floatx4 s0 = __builtin_amdgcn_mfma_f32_16x16x32_f16(aq, kc0, zf, 0, 0, 0);
    floatx4 s1 = __builtin_amdgcn_mfma_f32_16x16x32_f16(aq, kc1, zf, 0, 0, 0);

    float p0[4], p1[4];
#pragma unroll
    for (int r = 0; r < 4; r++) {
      p0[r] = fast_exp2(s0[r] * L2E);
      p1[r] = fast_exp2(s1[r] * L2E);
      lsum[r] += p0[r] + p1[r];
    }
#pragma unroll
    for (int r = 0; r < 4; r++) {
      int row = q4 * 4 + r;
      sPw[row * 40 + l15]      = f32_to_f16u(p0[r]);
      sPw[row * 40 + 16 + l15] = f32_to_f16u(p1[r]);
    }
    asm volatile("s_waitcnt lgkmcnt(0)" ::: "memory");  // own P writes visible

    // barrier: all P written, all V(it) landed (each wave vmcnt-waited above)
    __builtin_amdgcn_s_barrier();
    asm volatile("s_waitcnt lgkmcnt(0)" ::: "memory");  // fence: no read hoist

    // P-frags for ALL 64 n (rows nt*16+l15, k = m = q4*8+j)
    half8 ap[4];
#pragma unroll
    for (int nt = 0; nt < 4; nt++)
      ap[nt] = *(const half8*)&sP[nt * 640 + l15 * 40 + q4 * 8];

    const unsigned short* sVb = (const unsigned short*)(smem + bufoff);
#pragma unroll
    for (int ct = 0; ct < 4; ct++) {
      int co = w * 64 + ct * 16 + l15;
      half8 bv8 = *(const half8*)&sVb[co * 32 + ((q4 ^ ((co >> 1) & 3)) * 8)];
#pragma unroll
      for (int nt = 0; nt < 4; nt++)
        acc[ct * 4 + nt] = __builtin_amdgcn_mfma_f32_16x16x32_f16(ap[nt], bv8, acc[ct * 4 + nt], 0, 0, 0);
    }
    asm volatile("s_waitcnt lgkmcnt(0)" ::: "memory");  // reads done before reuse
    __builtin_amdgcn_s_barrier();

    kc0 = kn0; kc1 = kn1;
    bufoff ^= 16384;
  }

  // lsum reduce (S phase split by n: wave w owns rows n0+16w+..)
#pragma unroll
  for (int off = 1; off < 16; off <<= 1) {
#pragma unroll
    for (int r = 0; r < 4; r++) lsum[r] += __shfl_xor(lsum[r], off);
  }
  if (l15 == 0) {
#pragma unroll
    for (int r = 0; r < 4; r++)
      lW[((size_t)chunk * 4 + b) * 4096 + n0 + 16 * w + q4 * 4 + r] = lsum[r];
  }

  // epilogue: wave w owns co w*64..w*64+63, all 64 n.
  unsigned short* sO = (unsigned short*)smem;  // [128 co][pitch 72]
#pragma unroll
  for (int pass = 0; pass < 2; pass++) {
    __syncthreads();
    if ((w >> 1) == pass) {
#pragma unroll
      for (int ct = 0; ct < 4; ct++) {
        int co_l = (w & 1) * 64 + ct * 16 + l15;
#pragma unroll
        for (int nt = 0; nt < 4; nt++) {
#pragma unroll
          for (int r = 0; r < 4; r++) {
            int nl = nt * 16 + q4 * 4 + r;
            sO[co_l * 72 + nl] = f32_to_f16u(acc[ct * 4 + nt][r]);
          }
        }
      }
    }
    __syncthreads();
#pragma unroll
    for (int s = 0; s < 4; s++) {
      int co_l = s * 32 + (t >> 3);
      int ch = t & 7;
      int4 val = *(const int4*)&sO[co_l * 72 + ch * 8];
      *(int4*)&Op[(((size_t)chunk * 4 + b) * 256 + pass * 128 + co_l) * 4096 + n0 + ch * 8] = val;
    }
  }
}

// ---------------------------------------------------------------------------
// Combine: out[b][co][n] = sum_ch Op[ch][b][co][n] / sum_ch lW[ch][b][n]
// ---------------------------------------------------------------------------
__global__ __launch_bounds__(256) void combine_kernel(
    const unsigned short* __restrict__ Op,
    const float* __restrict__ lW,
    float* __restrict__ out)
{
  const int t = threadIdx.x;
  const int b = blockIdx.y;
  const size_t n8 = (size_t)blockIdx.x * 2048 + (size_t)t * 8;
  const int co0 = blockIdx.z * 4;

  float sum[8] = {0.f, 0.f, 0.f, 0.f, 0.f, 0.f, 0.f, 0.f};
#pragma unroll
  for (int ch = 0; ch < 4; ch++) {
    const float* lp = lW + ((size_t)ch * 4 + b) * 4096 + n8;
    float4 a0 = *(const float4*)lp;
    float4 a1 = *(const float4*)(lp + 4);
    sum[0] += a0.x; sum[1] += a0.y; sum[2] += a0.z; sum[3] += a0.w;
    sum[4] += a1.x; sum[5] += a1.y; sum[6] += a1.z; sum[7] += a1.w;
  }
  float rl[8];
#pragma unroll
  for (int i = 0; i < 8; i++) rl[i] = 1.0f / sum[i];

#pragma unroll
  for (int cc = 0; cc < 4; cc++) {
    int co = co0 + cc;
    float o[8] = {0.f, 0.f, 0.f, 0.f, 0.f, 0.f, 0.f, 0.f};
#pragma unroll
    for (int ch = 0; ch < 4; ch++) {
      half8 hv = *(const half8*)&Op[(((size_t)ch * 4 + b) * 256 + co) * 4096 + n8];
#pragma unroll
      for (int i = 0; i < 8; i++) o[i] += (float)hv[i];
    }
    float* op = out + ((size_t)b * 256 + co) * 4096 + n8;
    float4 r0, r1;
    r0.x = o[0] * rl[0]; r0.y = o[1] * rl[1]; r0.z = o[2] * rl[2]; r0.w = o[3] * rl[3];
    r1.x = o[4] * rl[4]; r1.y = o[5] * rl[5]; r1.z = o[6] * rl[6]; r1.w = o[7] * rl[7];
    *(float4*)op = r0;
    *(float4*)(op + 4) = r1;
  }
}

extern "C" void kernel_launch(void* const* d_in, const int* in_sizes, int n_in,
                              void* d_out, int out_size, void* d_ws, size_t ws_size,
                              hipStream_t stream) {
  const float* rgb   = (const float*)d_in[0];
  const float* depth = (const float*)d_in[1];
  const float* Wq    = (const float*)d_in[2];
  const float* bq    = (const float*)d_in[3];
  const float* Wk    = (const float*)d_in[4];
  const float* bk    = (const float*)d_in[5];
  const float* Wv    = (const float*)d_in[6];
  const float* bv    = (const float*)d_in[7];
  float* out = (float*)d_out;

  unsigned short* qT = (unsigned short*)d_ws;             // 1 MB
  unsigned short* kT = qT + (size_t)4 * 4096 * 32;        // 1 MB
  unsigned short* vW = kT + (size_t)4 * 4096 * 32;        // 8 MB
  unsigned short* Op = vW + (size_t)4 * 256 * 4096;       // 33.5 MB (4 chunks)
  float* lW = (float*)(Op + (size_t)4 * 4 * 256 * 4096);  // 256 KB

  dim3 pg(64, 4, 3);
  proj_kernel<<<pg, 256, 0, stream>>>(rgb, depth, Wq, bq, Wk, bk, Wv, bv, qT, kT, vW);
  attn_kernel<<<dim3(1024, 1, 1), 256, 0, stream>>>(qT, kT, vW, Op, lW);
  dim3 cg(2, 4, 64);
  combine_kernel<<<cg, 256, 0, stream>>>(Op, lW, out);
}